// Round 4
// baseline (135.485 us; speedup 1.0000x reference)
//
#include <hip/hip_runtime.h>
#include <hip/hip_bf16.h>

// Problem constants
// B=32768, P=8; aff/mat vocab 16 -> 256 (aff,mat) pairs
// part table: 256 pairs x 256 outputs (bf16)
// obj GEMM: pooled[B,256] @ W_obj[:,192:448]^T

typedef float          f32x4  __attribute__((ext_vector_type(4)));
typedef short          s16x8  __attribute__((ext_vector_type(8)));
typedef unsigned short u16x8  __attribute__((ext_vector_type(8)));

__device__ __forceinline__ unsigned short f2bf_rne(float x) {
    unsigned u = __float_as_uint(x);
    u += 0x7FFFu + ((u >> 16) & 1u);
    return (unsigned short)(u >> 16);
}

// ws layout (bytes)
#define WS_PART_TABLE 0          // 256*256 short = 131072
#define WS_WP2T       131072     // 256*256 short = 131072  (W_obj[:,192:448] transposed-to-[n][k], bf16)
#define WS_TT         262144     // 16*256 f32 (b_obj folded in)
#define WS_TO         278528     // 64*256 f32
#define WS_TS         344064     // 32*256 f32
// total = 376832 bytes

__global__ __launch_bounds__(256) void precompute_kernel(
    const float* __restrict__ aff_emb, const float* __restrict__ mat_emb,
    const float* __restrict__ task_emb, const float* __restrict__ obj_emb,
    const float* __restrict__ state_emb,
    const float* __restrict__ W_part, const float* __restrict__ b_part,
    const float* __restrict__ W_obj, const float* __restrict__ b_obj,
    char* __restrict__ ws)
{
    short* part_table = (short*)(ws + WS_PART_TABLE);
    short* wp2t       = (short*)(ws + WS_WP2T);
    float* Tt         = (float*)(ws + WS_TT);
    float* To         = (float*)(ws + WS_TO);
    float* Ts         = (float*)(ws + WS_TS);

    int bid = blockIdx.x, tid = threadIdx.x;
    __shared__ float rowv[128];

    if (bid < 256) {
        // part table: pair = a*16+m
        int a = bid >> 4, m = bid & 15;
        if (tid < 64)       rowv[tid] = aff_emb[a*64 + tid];
        else if (tid < 128) rowv[tid] = mat_emb[m*64 + (tid-64)];
        __syncthreads();
        float s = b_part[tid];
        const float* w = &W_part[tid*128];
        #pragma unroll
        for (int k = 0; k < 128; k += 4) {
            float4 wv = *(const float4*)&w[k];
            s += rowv[k]*wv.x + rowv[k+1]*wv.y + rowv[k+2]*wv.z + rowv[k+3]*wv.w;
        }
        part_table[bid*256 + tid] = (short)f2bf_rne(fmaxf(s, 0.f));
    } else if (bid < 368) {
        // categorical tables
        int rr = bid - 256;
        const float* emb; int koff; float* dst;
        if (rr < 16)      { emb = &task_emb[rr*64];        koff = 0;   dst = &Tt[rr*256]; }
        else if (rr < 80) { emb = &obj_emb[(rr-16)*64];    koff = 64;  dst = &To[(rr-16)*256]; }
        else              { emb = &state_emb[(rr-80)*64];  koff = 128; dst = &Ts[(rr-80)*256]; }
        if (tid < 64) rowv[tid] = emb[tid];
        __syncthreads();
        float s = (rr < 16) ? b_obj[tid] : 0.f;
        const float* w = &W_obj[tid*448 + koff];
        #pragma unroll
        for (int k = 0; k < 64; k += 4) {
            float4 wv = *(const float4*)&w[k];
            s += rowv[k]*wv.x + rowv[k+1]*wv.y + rowv[k+2]*wv.z + rowv[k+3]*wv.w;
        }
        dst[tid] = s;
    } else {
        // W_obj[:,192:448] -> wp2t[n][k] bf16
        int n = bid - 368;
        wp2t[n*256 + tid] = (short)f2bf_rne(W_obj[n*448 + 192 + tid]);
    }
}

// One 16-row tile per block; 2048 blocks. B-fragments loaded from L2-hot wp2t
// inside the MFMA loop (no persistent 128-VGPR bfrag). launch_bounds(256,4):
// <=128 VGPR -> 4 waves/SIMD -> 4 blocks/CU of latency hiding.
__global__ __launch_bounds__(256, 4) void main_kernel(
    const int* __restrict__ aff_idx, const int* __restrict__ mat_idx,
    const int* __restrict__ task_idx, const int* __restrict__ obj_idx,
    const int* __restrict__ state_idx,
    const char* __restrict__ ws, float* __restrict__ out)
{
    const short* part_table = (const short*)(ws + WS_PART_TABLE);
    const short* wp2t       = (const short*)(ws + WS_WP2T);
    const float* Tt         = (const float*)(ws + WS_TT);
    const float* To         = (const float*)(ws + WS_TO);
    const float* Ts         = (const float*)(ws + WS_TS);

    __shared__ short pooled[16*264];   // 16 rows x 256 elems, padded stride 264
    __shared__ int   pair_s[16*8];
    __shared__ int   tos_s[48];        // [3][16] task/obj/state per row

    int tid  = threadIdx.x;
    int wave = tid >> 6, lane = tid & 63;
    int l15 = lane & 15, l4 = lane >> 4;

    int row0 = blockIdx.x * 16;

    if (tid < 128) {
        int r = tid >> 3, j = tid & 7;
        int a = aff_idx[(row0+r)*8 + j];
        int m = mat_idx[(row0+r)*8 + j];
        pair_s[r*8 + j] = (a*16 + m) * 256;   // element offset into part_table
    } else if (tid < 176) {
        int u = tid - 128;
        int r = u & 15, wh = u >> 4;
        int row = row0 + r;
        int v = (wh == 0) ? task_idx[row] : (wh == 1) ? obj_idx[row] : state_idx[row];
        tos_s[wh*16 + r] = v;
    }
    __syncthreads();

    // ---- pooling: thread (r = tid>>4, e = tid&15) covers elems [e*16, e*16+16) of row r
    // ReLU'd bf16 entries are non-negative -> bit pattern order == numeric order
    // -> packed unsigned 16-bit max == float max, and result is already bf16 bits.
    {
        int r = tid >> 4, e = tid & 15;
        u16x8 mx0 = (u16x8)(0), mx1 = (u16x8)(0);
        #pragma unroll
        for (int p = 0; p < 8; ++p) {
            int off = pair_s[r*8 + p] + e*16;
            u16x8 v0 = *(const u16x8*)&part_table[off];
            u16x8 v1 = *(const u16x8*)&part_table[off + 8];
            mx0 = __builtin_elementwise_max(mx0, v0);
            mx1 = __builtin_elementwise_max(mx1, v1);
        }
        *(u16x8*)&pooled[r*264 + e*16]     = mx0;
        *(u16x8*)&pooled[r*264 + e*16 + 8] = mx1;
    }
    __syncthreads();

    // ---- MFMA: D[16 rows][16 cols] per n-tile
    // A: row = lane&15, k = (lane>>4)*8+j ; B: col = lane&15, same k
    f32x4 acc[4];
    #pragma unroll
    for (int nt = 0; nt < 4; ++nt) acc[nt] = (f32x4){0.f, 0.f, 0.f, 0.f};

    const short* bbase = &wp2t[(wave*64 + l15)*256 + l4*8];
    #pragma unroll
    for (int ks = 0; ks < 8; ++ks) {
        s16x8 af = *(const s16x8*)&pooled[l15*264 + ks*32 + l4*8];
        #pragma unroll
        for (int nt = 0; nt < 4; ++nt) {
            s16x8 bf = *(const s16x8*)&bbase[nt*16*256 + ks*32];
            acc[nt] = __builtin_amdgcn_mfma_f32_16x16x32_bf16(af, bf, acc[nt], 0, 0, 0);
        }
    }

    // ---- epilogue: C/D layout col = lane&15, row = (lane>>4)*4 + reg
    #pragma unroll
    for (int nt = 0; nt < 4; ++nt) {
        int col = wave*64 + nt*16 + l15;
        #pragma unroll
        for (int reg = 0; reg < 4; ++reg) {
            int rl  = l4*4 + reg;
            int row = row0 + rl;
            int t = tos_s[rl], o = tos_s[16 + rl], s = tos_s[32 + rl];
            float v = acc[nt][reg] + Tt[t*256 + col] + To[o*256 + col] + Ts[s*256 + col];
            out[row*256 + col] = fmaxf(v, 0.f);
        }
    }
}

extern "C" void kernel_launch(void* const* d_in, const int* in_sizes, int n_in,
                              void* d_out, int out_size, void* d_ws, size_t ws_size,
                              hipStream_t stream) {
    const int*   aff_idx   = (const int*)d_in[0];
    const int*   mat_idx   = (const int*)d_in[1];
    const int*   task_idx  = (const int*)d_in[2];
    const int*   obj_idx   = (const int*)d_in[3];
    const int*   state_idx = (const int*)d_in[4];
    const float* aff_emb   = (const float*)d_in[5];
    const float* mat_emb   = (const float*)d_in[6];
    const float* task_emb  = (const float*)d_in[7];
    const float* obj_emb   = (const float*)d_in[8];
    const float* state_emb = (const float*)d_in[9];
    const float* W_part    = (const float*)d_in[10];
    const float* b_part    = (const float*)d_in[11];
    const float* W_obj     = (const float*)d_in[12];
    const float* b_obj     = (const float*)d_in[13];

    precompute_kernel<<<624, 256, 0, stream>>>(
        aff_emb, mat_emb, task_emb, obj_emb, state_emb,
        W_part, b_part, W_obj, b_obj, (char*)d_ws);

    main_kernel<<<2048, 256, 0, stream>>>(
        aff_idx, mat_idx, task_idx, obj_idx, state_idx,
        (const char*)d_ws, (float*)d_out);
}

// Round 7
// 133.559 us; speedup vs baseline: 1.0144x; 1.0144x over previous
//
#include <hip/hip_runtime.h>
#include <hip/hip_bf16.h>

// Problem constants
// B=32768, P=8; aff/mat vocab 16 -> 256 (aff,mat) pairs
// part table: 256 pairs x 256 outputs (bf16)
// obj GEMM: pooled[B,256] @ W_obj[:,192:448]^T

typedef float          f32x4  __attribute__((ext_vector_type(4)));
typedef short          s16x8  __attribute__((ext_vector_type(8)));
typedef unsigned short u16x8  __attribute__((ext_vector_type(8)));

__device__ __forceinline__ unsigned short f2bf_rne(float x) {
    unsigned u = __float_as_uint(x);
    u += 0x7FFFu + ((u >> 16) & 1u);
    return (unsigned short)(u >> 16);
}

// ws layout (bytes)
#define WS_PART_TABLE 0          // 256*256 short = 131072
#define WS_WP2T       131072     // 256*256 short = 131072  (W_obj[:,192:448] transposed-to-[n][k], bf16)
#define WS_TT         262144     // 16*256 f32 (b_obj folded in)
#define WS_TO         278528     // 64*256 f32
#define WS_TS         344064     // 32*256 f32
// total = 376832 bytes

__global__ __launch_bounds__(256) void precompute_kernel(
    const float* __restrict__ aff_emb, const float* __restrict__ mat_emb,
    const float* __restrict__ task_emb, const float* __restrict__ obj_emb,
    const float* __restrict__ state_emb,
    const float* __restrict__ W_part, const float* __restrict__ b_part,
    const float* __restrict__ W_obj, const float* __restrict__ b_obj,
    char* __restrict__ ws)
{
    short* part_table = (short*)(ws + WS_PART_TABLE);
    short* wp2t       = (short*)(ws + WS_WP2T);
    float* Tt         = (float*)(ws + WS_TT);
    float* To         = (float*)(ws + WS_TO);
    float* Ts         = (float*)(ws + WS_TS);

    int bid = blockIdx.x, tid = threadIdx.x;
    __shared__ float rowv[128];

    if (bid < 256) {
        // part table: pair = a*16+m
        int a = bid >> 4, m = bid & 15;
        if (tid < 64)       rowv[tid] = aff_emb[a*64 + tid];
        else if (tid < 128) rowv[tid] = mat_emb[m*64 + (tid-64)];
        __syncthreads();
        float s = b_part[tid];
        const float* w = &W_part[tid*128];
        #pragma unroll
        for (int k = 0; k < 128; k += 4) {
            float4 wv = *(const float4*)&w[k];
            s += rowv[k]*wv.x + rowv[k+1]*wv.y + rowv[k+2]*wv.z + rowv[k+3]*wv.w;
        }
        part_table[bid*256 + tid] = (short)f2bf_rne(fmaxf(s, 0.f));
    } else if (bid < 368) {
        // categorical tables
        int rr = bid - 256;
        const float* emb; int koff; float* dst;
        if (rr < 16)      { emb = &task_emb[rr*64];        koff = 0;   dst = &Tt[rr*256]; }
        else if (rr < 80) { emb = &obj_emb[(rr-16)*64];    koff = 64;  dst = &To[(rr-16)*256]; }
        else              { emb = &state_emb[(rr-80)*64];  koff = 128; dst = &Ts[(rr-80)*256]; }
        if (tid < 64) rowv[tid] = emb[tid];
        __syncthreads();
        float s = (rr < 16) ? b_obj[tid] : 0.f;
        const float* w = &W_obj[tid*448 + koff];
        #pragma unroll
        for (int k = 0; k < 64; k += 4) {
            float4 wv = *(const float4*)&w[k];
            s += rowv[k]*wv.x + rowv[k+1]*wv.y + rowv[k+2]*wv.z + rowv[k+3]*wv.w;
        }
        dst[tid] = s;
    } else {
        // W_obj[:,192:448] -> wp2t[n][k] bf16
        int n = bid - 368;
        wp2t[n*256 + tid] = (short)f2bf_rne(W_obj[n*448 + 192 + tid]);
    }
}

// One 16-row tile per block; 2048 blocks. Round-4 structure (late epilogue
// gathers, twice-green) with plain __launch_bounds__(256): isolates whether
// the min-waves attribute was capping OccupancyPercent at ~49%.
__global__ __launch_bounds__(256) void main_kernel(
    const int* __restrict__ aff_idx, const int* __restrict__ mat_idx,
    const int* __restrict__ task_idx, const int* __restrict__ obj_idx,
    const int* __restrict__ state_idx,
    const char* __restrict__ ws, float* __restrict__ out)
{
    const short* part_table = (const short*)(ws + WS_PART_TABLE);
    const short* wp2t       = (const short*)(ws + WS_WP2T);
    const float* Tt         = (const float*)(ws + WS_TT);
    const float* To         = (const float*)(ws + WS_TO);
    const float* Ts         = (const float*)(ws + WS_TS);

    __shared__ short pooled[16*264];   // 16 rows x 256 elems, padded stride 264
    __shared__ int   pair_s[16*8];
    __shared__ int   tos_s[48];        // [3][16] task/obj/state per row

    int tid  = threadIdx.x;
    int wave = tid >> 6, lane = tid & 63;
    int l15 = lane & 15, l4 = lane >> 4;

    int row0 = blockIdx.x * 16;

    if (tid < 128) {
        int r = tid >> 3, j = tid & 7;
        int a = aff_idx[(row0+r)*8 + j];
        int m = mat_idx[(row0+r)*8 + j];
        pair_s[r*8 + j] = (a*16 + m) * 256;   // element offset into part_table
    } else if (tid < 176) {
        int u = tid - 128;
        int r = u & 15, wh = u >> 4;
        int row = row0 + r;
        int v = (wh == 0) ? task_idx[row] : (wh == 1) ? obj_idx[row] : state_idx[row];
        tos_s[wh*16 + r] = v;
    }
    __syncthreads();

    // ---- pooling: thread (r = tid>>4, e = tid&15) covers elems [e*16, e*16+16) of row r
    // ReLU'd bf16 entries are non-negative -> bit pattern order == numeric order
    // -> packed unsigned 16-bit max == float max, and result is already bf16 bits.
    {
        int r = tid >> 4, e = tid & 15;
        u16x8 mx0 = (u16x8)(0), mx1 = (u16x8)(0);
        #pragma unroll
        for (int p = 0; p < 8; ++p) {
            int off = pair_s[r*8 + p] + e*16;
            u16x8 v0 = *(const u16x8*)&part_table[off];
            u16x8 v1 = *(const u16x8*)&part_table[off + 8];
            mx0 = __builtin_elementwise_max(mx0, v0);
            mx1 = __builtin_elementwise_max(mx1, v1);
        }
        *(u16x8*)&pooled[r*264 + e*16]     = mx0;
        *(u16x8*)&pooled[r*264 + e*16 + 8] = mx1;
    }
    __syncthreads();

    // ---- MFMA: D[16 rows][16 cols] per n-tile
    // A: row = lane&15, k = (lane>>4)*8+j ; B: col = lane&15, same k
    f32x4 acc[4];
    #pragma unroll
    for (int nt = 0; nt < 4; ++nt) acc[nt] = (f32x4){0.f, 0.f, 0.f, 0.f};

    const short* bbase = &wp2t[(wave*64 + l15)*256 + l4*8];
    #pragma unroll
    for (int ks = 0; ks < 8; ++ks) {
        s16x8 af = *(const s16x8*)&pooled[l15*264 + ks*32 + l4*8];
        #pragma unroll
        for (int nt = 0; nt < 4; ++nt) {
            s16x8 bf = *(const s16x8*)&bbase[nt*16*256 + ks*32];
            acc[nt] = __builtin_amdgcn_mfma_f32_16x16x32_bf16(af, bf, acc[nt], 0, 0, 0);
        }
    }

    // ---- epilogue: C/D layout col = lane&15, row = (lane>>4)*4 + reg
    #pragma unroll
    for (int nt = 0; nt < 4; ++nt) {
        int col = wave*64 + nt*16 + l15;
        #pragma unroll
        for (int reg = 0; reg < 4; ++reg) {
            int rl  = l4*4 + reg;
            int row = row0 + rl;
            int t = tos_s[rl], o = tos_s[16 + rl], s = tos_s[32 + rl];
            float v = acc[nt][reg] + Tt[t*256 + col] + To[o*256 + col] + Ts[s*256 + col];
            out[row*256 + col] = fmaxf(v, 0.f);
        }
    }
}

extern "C" void kernel_launch(void* const* d_in, const int* in_sizes, int n_in,
                              void* d_out, int out_size, void* d_ws, size_t ws_size,
                              hipStream_t stream) {
    const int*   aff_idx   = (const int*)d_in[0];
    const int*   mat_idx   = (const int*)d_in[1];
    const int*   task_idx  = (const int*)d_in[2];
    const int*   obj_idx   = (const int*)d_in[3];
    const int*   state_idx = (const int*)d_in[4];
    const float* aff_emb   = (const float*)d_in[5];
    const float* mat_emb   = (const float*)d_in[6];
    const float* task_emb  = (const float*)d_in[7];
    const float* obj_emb   = (const float*)d_in[8];
    const float* state_emb = (const float*)d_in[9];
    const float* W_part    = (const float*)d_in[10];
    const float* b_part    = (const float*)d_in[11];
    const float* W_obj     = (const float*)d_in[12];
    const float* b_obj     = (const float*)d_in[13];

    precompute_kernel<<<624, 256, 0, stream>>>(
        aff_emb, mat_emb, task_emb, obj_emb, state_emb,
        W_part, b_part, W_obj, b_obj, (char*)d_ws);

    main_kernel<<<2048, 256, 0, stream>>>(
        aff_idx, mat_idx, task_idx, obj_idx, state_idx,
        (const char*)d_ws, (float*)d_out);
}

// Round 10
// 113.025 us; speedup vs baseline: 1.1987x; 1.1817x over previous
//
#include <hip/hip_runtime.h>
#include <hip/hip_bf16.h>

// Problem constants
// B=32768, P=8; aff/mat vocab 16 -> 256 (aff,mat) pairs
// part table: 256 pairs x 256 outputs (bf16)
// obj GEMM: pooled[B,256] @ W_obj[:,192:448]^T
//
// main_kernel: 256 blocks x 1024 threads, 128 rows/block (8 tiles of 16).
// Persistent B in VGPR (loaded once), cat tables staged in LDS once,
// pooling prefetched one tile ahead.

typedef float          f32x4  __attribute__((ext_vector_type(4)));
typedef short          s16x8  __attribute__((ext_vector_type(8)));
typedef unsigned short u16x8  __attribute__((ext_vector_type(8)));
typedef unsigned short u16x4  __attribute__((ext_vector_type(4)));

__device__ __forceinline__ unsigned short f2bf_rne(float x) {
    unsigned u = __float_as_uint(x);
    u += 0x7FFFu + ((u >> 16) & 1u);
    return (unsigned short)(u >> 16);
}

// ws layout (bytes)
#define WS_PART_TABLE 0          // 256*256 short = 131072
#define WS_WP2T       131072     // 256*256 short = 131072  (W_obj[:,192:448] as [n][k], bf16)
#define WS_TT         262144     // 16*256 f32 (b_obj folded in)   -- contiguous with
#define WS_TO         278528     // 64*256 f32                     -- To and
#define WS_TS         344064     // 32*256 f32                     -- Ts (112 rows total)
// total = 376832 bytes

__global__ __launch_bounds__(256) void precompute_kernel(
    const float* __restrict__ aff_emb, const float* __restrict__ mat_emb,
    const float* __restrict__ task_emb, const float* __restrict__ obj_emb,
    const float* __restrict__ state_emb,
    const float* __restrict__ W_part, const float* __restrict__ b_part,
    const float* __restrict__ W_obj, const float* __restrict__ b_obj,
    char* __restrict__ ws)
{
    short* part_table = (short*)(ws + WS_PART_TABLE);
    short* wp2t       = (short*)(ws + WS_WP2T);
    float* Tt         = (float*)(ws + WS_TT);
    float* To         = (float*)(ws + WS_TO);
    float* Ts         = (float*)(ws + WS_TS);

    int bid = blockIdx.x, tid = threadIdx.x;
    __shared__ float rowv[128];

    if (bid < 256) {
        // part table: pair = a*16+m
        int a = bid >> 4, m = bid & 15;
        if (tid < 64)       rowv[tid] = aff_emb[a*64 + tid];
        else if (tid < 128) rowv[tid] = mat_emb[m*64 + (tid-64)];
        __syncthreads();
        float s = b_part[tid];
        const float* w = &W_part[tid*128];
        #pragma unroll
        for (int k = 0; k < 128; k += 4) {
            float4 wv = *(const float4*)&w[k];
            s += rowv[k]*wv.x + rowv[k+1]*wv.y + rowv[k+2]*wv.z + rowv[k+3]*wv.w;
        }
        part_table[bid*256 + tid] = (short)f2bf_rne(fmaxf(s, 0.f));
    } else if (bid < 368) {
        // categorical tables
        int rr = bid - 256;
        const float* emb; int koff; float* dst;
        if (rr < 16)      { emb = &task_emb[rr*64];        koff = 0;   dst = &Tt[rr*256]; }
        else if (rr < 80) { emb = &obj_emb[(rr-16)*64];    koff = 64;  dst = &To[(rr-16)*256]; }
        else              { emb = &state_emb[(rr-80)*64];  koff = 128; dst = &Ts[(rr-80)*256]; }
        if (tid < 64) rowv[tid] = emb[tid];
        __syncthreads();
        float s = (rr < 16) ? b_obj[tid] : 0.f;
        const float* w = &W_obj[tid*448 + koff];
        #pragma unroll
        for (int k = 0; k < 64; k += 4) {
            float4 wv = *(const float4*)&w[k];
            s += rowv[k]*wv.x + rowv[k+1]*wv.y + rowv[k+2]*wv.z + rowv[k+3]*wv.w;
        }
        dst[tid] = s;
    } else {
        // W_obj[:,192:448] -> wp2t[n][k] bf16
        int n = bid - 368;
        wp2t[n*256 + tid] = (short)f2bf_rne(W_obj[n*448 + 192 + tid]);
    }
}

__global__ __launch_bounds__(1024, 4) void main_kernel(
    const int* __restrict__ aff_idx, const int* __restrict__ mat_idx,
    const int* __restrict__ task_idx, const int* __restrict__ obj_idx,
    const int* __restrict__ state_idx,
    const char* __restrict__ ws, float* __restrict__ out)
{
    const short* part_table = (const short*)(ws + WS_PART_TABLE);
    const short* wp2t       = (const short*)(ws + WS_WP2T);

    // LDS: 114688 + 8448 + 4096 + 1536 = 128768 B (125.8 KiB)
    __shared__ float catL[112*256];    // rows: Tt[0..15] | To[16..79] | Ts[80..111]
    __shared__ short pooled[16*264];   // 16 rows x 256 elems, stride 264
    __shared__ int   pair_all[128*8];  // part_table element offsets, all 128 rows
    __shared__ int   tos_all[3*128];   // task/obj/state per row

    int tid  = threadIdx.x;
    int wv   = tid >> 6, lane = tid & 63;
    int l15  = lane & 15, l4 = lane >> 4;
    int row0 = blockIdx.x * 128;

    // ---- stage cat tables (contiguous 112*256 f32 in ws) as float4
    {
        const float4* csrc = (const float4*)(ws + WS_TT);
        float4* cdst = (float4*)catL;
        #pragma unroll
        for (int k = 0; k < 7; ++k)
            cdst[tid + k*1024] = csrc[tid + k*1024];
    }
    // ---- stage indices: 1024 threads == 128 rows x 8 parts exactly
    {
        int a = aff_idx[row0*8 + tid];
        int m = mat_idx[row0*8 + tid];
        pair_all[tid] = (a*16 + m) * 256;
    }
    if (tid < 384) {
        int wh = tid >> 7, r = tid & 127;
        const int* p = (wh == 0) ? task_idx : (wh == 1) ? obj_idx : state_idx;
        tos_all[wh*128 + r] = p[row0 + r];
    }

    // ---- persistent B fragments: wave wv owns output cols [wv*16, wv*16+16)
    // B[k][n]: col = lane&15 (n = wv*16+l15), k = ks*32 + (lane>>4)*8 + j
    s16x8 bfrag[8];
    #pragma unroll
    for (int ks = 0; ks < 8; ++ks)
        bfrag[ks] = *(const s16x8*)&wp2t[(wv*16 + l15)*256 + ks*32 + l4*8];

    __syncthreads();

    // ---- pooling prefetch for tile 0: thread (pr = tid>>6, pe = tid&63)
    // covers elems [pe*4, pe*4+4) of row pr (u16x4 = 8B loads)
    int pr = tid >> 6, pe = tid & 63;
    u16x4 pl[8];
    #pragma unroll
    for (int p = 0; p < 8; ++p)
        pl[p] = *(const u16x4*)&part_table[pair_all[pr*8 + p] + pe*4];

    for (int t = 0; t < 8; ++t) {
        // reduce prefetched pool loads; write pooled.
        // ReLU'd bf16 is non-negative: u16 bit order == float order, result
        // is already bf16 bits (exact).
        u16x4 mx = pl[0];
        #pragma unroll
        for (int p = 1; p < 8; ++p) mx = __builtin_elementwise_max(mx, pl[p]);
        *(u16x4*)&pooled[pr*264 + pe*4] = mx;
        __syncthreads();

        // prefetch next tile's pool loads (in flight during MFMA + epilogue)
        if (t < 7) {
            #pragma unroll
            for (int p = 0; p < 8; ++p)
                pl[p] = *(const u16x4*)&part_table[pair_all[((t+1)*16 + pr)*8 + p] + pe*4];
        }

        // MFMA: D[16 rows][16 cols]; A row = lane&15, k = (lane>>4)*8+j
        f32x4 acc = (f32x4){0.f, 0.f, 0.f, 0.f};
        #pragma unroll
        for (int ks = 0; ks < 8; ++ks) {
            s16x8 af = *(const s16x8*)&pooled[l15*264 + ks*32 + l4*8];
            acc = __builtin_amdgcn_mfma_f32_16x16x32_bf16(af, bfrag[ks], acc, 0, 0, 0);
        }

        // epilogue: C/D col = lane&15, row = (lane>>4)*4 + reg; cat from LDS
        int col = wv*16 + l15;
        #pragma unroll
        for (int reg = 0; reg < 4; ++reg) {
            int rl = l4*4 + reg;
            int ti = tos_all[t*16 + rl];
            int oi = tos_all[128 + t*16 + rl];
            int si = tos_all[256 + t*16 + rl];
            float v = acc[reg] + catL[ti*256 + col]
                               + catL[(16 + oi)*256 + col]
                               + catL[(80 + si)*256 + col];
            out[(row0 + t*16 + rl)*256 + col] = fmaxf(v, 0.f);
        }
        __syncthreads();   // all waves done reading pooled before next overwrite
    }
}

extern "C" void kernel_launch(void* const* d_in, const int* in_sizes, int n_in,
                              void* d_out, int out_size, void* d_ws, size_t ws_size,
                              hipStream_t stream) {
    const int*   aff_idx   = (const int*)d_in[0];
    const int*   mat_idx   = (const int*)d_in[1];
    const int*   task_idx  = (const int*)d_in[2];
    const int*   obj_idx   = (const int*)d_in[3];
    const int*   state_idx = (const int*)d_in[4];
    const float* aff_emb   = (const float*)d_in[5];
    const float* mat_emb   = (const float*)d_in[6];
    const float* task_emb  = (const float*)d_in[7];
    const float* obj_emb   = (const float*)d_in[8];
    const float* state_emb = (const float*)d_in[9];
    const float* W_part    = (const float*)d_in[10];
    const float* b_part    = (const float*)d_in[11];
    const float* W_obj     = (const float*)d_in[12];
    const float* b_obj     = (const float*)d_in[13];

    precompute_kernel<<<624, 256, 0, stream>>>(
        aff_emb, mat_emb, task_emb, obj_emb, state_emb,
        W_part, b_part, W_obj, b_obj, (char*)d_ws);

    main_kernel<<<256, 1024, 0, stream>>>(
        aff_idx, mat_idx, task_idx, obj_idx, state_idx,
        (const char*)d_ws, (float*)d_out);
}